// Round 5
// baseline (486.010 us; speedup 1.0000x reference)
//
#include <hip/hip_runtime.h>
#include <hip/hip_bf16.h>
#include <math.h>

#define NB 16
#define NT 96
#define NC 3
#define ND 64
#define NJ 192   // C*D
#define NHID 512
#define NF 48
#define NS 17

// ---------------- K1: mean over (H,W): x[B,T,C,16,16,64] -> xm[B,T,192] ----------------
// One block per (b,t,c): 4096 float4, 256 threads x 16 iters, coalesced. BW-bound.
__global__ __launch_bounds__(256) void k_mean(const float* __restrict__ x,
                                              float* __restrict__ xm) {
    const int blk = blockIdx.x;                 // (b*NT+t)*NC + c
    const int tid = threadIdx.x;
    const float4* xin = reinterpret_cast<const float4*>(x) + (size_t)blk * 4096;
    float4 acc = make_float4(0.f, 0.f, 0.f, 0.f);
#pragma unroll
    for (int k = 0; k < 16; ++k) {
        float4 v = xin[k * 256 + tid];
        acc.x += v.x; acc.y += v.y; acc.z += v.z; acc.w += v.w;
    }
    __shared__ float4 sums[256];
    sums[tid] = acc;
    __syncthreads();
    if (tid < 16) {
        float4 tot = make_float4(0.f, 0.f, 0.f, 0.f);
#pragma unroll
        for (int g = 0; g < 16; ++g) {
            float4 v = sums[g * 16 + tid];
            tot.x += v.x; tot.y += v.y; tot.z += v.z; tot.w += v.w;
        }
        const float s = 1.0f / 256.0f;
        tot.x *= s; tot.y *= s; tot.z *= s; tot.w *= s;
        const int c  = blk % NC;
        const int bt = blk / NC;
        float4* out = reinterpret_cast<float4*>(xm + (size_t)bt * NJ + c * ND);
        out[tid] = tot;
    }
}

// ---------------- K2: DFT with incremental rotation, output PT[b][j][f] = float2{re,im} ----
// PT[b,j,f] = (1/sqrt96) * sum_t xm[b,t,j] e^{-i 2pi (f+1) t/96}
// Block per (b, jc of 4 j); 192 threads = (jj 0..3) x (f 0..47). 1 sincosf/thread.
__global__ __launch_bounds__(192) void k_dft(const float* __restrict__ xm,
                                             float2* __restrict__ PT) {
    const int b  = blockIdx.x / NF;
    const int jc = blockIdx.x % NF;
    const int tid = threadIdx.x;
    const int f  = tid % 48;
    const int jj = tid / 48;
    __shared__ float xs[NT][4];
    for (int i = tid; i < NT * 4; i += 192) {
        const int t = i >> 2, j4 = i & 3;
        xs[t][j4] = xm[((size_t)b * NT + t) * NJ + jc * 4 + j4];
    }
    __syncthreads();
    const float th = (2.0f * 3.14159265358979323846f / 96.0f) * (float)(f + 1);
    float s0, c0;
    sincosf(th, &s0, &c0);
    float c = 1.f, s = 0.f;        // rotates through cos/sin((f+1)*t*2pi/96)
    float re = 0.f, im = 0.f;
    for (int t = 0; t < NT; ++t) {
        const float xv = xs[t][jj];
        re = fmaf(xv, c, re);
        im = fmaf(xv, s, im);
        const float cn = c * c0 - s * s0;
        s = s * c0 + c * s0;       // uses old c (cn not yet committed)
        c = cn;
    }
    const float inv = 0.1020620726159657f;  // 1/sqrt(96)
    const int j = jc * 4 + jj;
    PT[((size_t)b * NJ + j) * NF + f] = make_float2(re * inv, -im * inv);  // coalesced 8B/lane
}

// ---------------- K3: amp[b,o,f] = |sum_j in_w[o,j] * PT[b,j,f]| ----------------
// Grid 256 = (b 16) x (ot 16, O-tile 32). 192 thr: og=tid&7 (4 o each), fg=tid>>3 (2 f each).
// Per j: 1 ds_read_b128 of wcT (16B-aligned, conflict-free) + 1 coalesced global float4 of PT
// + 16 FMA  ->  VALU-bound (~2 cyc/FMA), no LDS bottleneck, no partial buffers.
__global__ __launch_bounds__(192) void k_amp(const float* __restrict__ in_w,
                                             const float2* __restrict__ PT,
                                             float* __restrict__ amp) {
    const int b  = blockIdx.x >> 4;
    const int ot = blockIdx.x & 15;
    const int tid = threadIdx.x;
    const int og = tid & 7;            // o = ot*32 + og*4 + r
    const int fg = tid >> 3;           // f = fg*2 + {0,1}
    __shared__ float wcT[NJ][36];      // [j][o_local], row = 144 B (16B-aligned), 27.6 KB
    for (int k = 0; k < 32; ++k) {     // stage in_w transposed; read coalesced (jj = tid)
        wcT[tid][k] = in_w[(size_t)(ot * 32 + k) * NJ + tid];
    }
    __syncthreads();
    const float2* ptb = PT + (size_t)b * NJ * NF;
    float re0[4] = {0.f,0.f,0.f,0.f}, im0[4] = {0.f,0.f,0.f,0.f};
    float re1[4] = {0.f,0.f,0.f,0.f}, im1[4] = {0.f,0.f,0.f,0.f};
#pragma unroll 4
    for (int j = 0; j < NJ; ++j) {
        const float4 p  = *reinterpret_cast<const float4*>(&ptb[(size_t)j * NF + fg * 2]);
        const float4 w4 = *reinterpret_cast<const float4*>(&wcT[j][og * 4]);
        const float wv[4] = {w4.x, w4.y, w4.z, w4.w};
#pragma unroll
        for (int r = 0; r < 4; ++r) {
            re0[r] = fmaf(wv[r], p.x, re0[r]);
            im0[r] = fmaf(wv[r], p.y, im0[r]);
            re1[r] = fmaf(wv[r], p.z, re1[r]);
            im1[r] = fmaf(wv[r], p.w, im1[r]);
        }
    }
#pragma unroll
    for (int r = 0; r < 4; ++r) {
        const int o = ot * 32 + og * 4 + r;
        float2 a;
        a.x = sqrtf(re0[r] * re0[r] + im0[r] * im0[r]);
        a.y = sqrtf(re1[r] * re1[r] + im1[r] * im1[r]);
        *reinterpret_cast<float2*>(&amp[((size_t)b * NHID + o) * NF + fg * 2]) = a;
    }
}

// ---------------- K4: weights + top-k fused. Block per b, 512 threads (one per o). ----
// wg/wn read from GLOBAL with wave-uniform addresses (scalar-load path, K$-hot, frees LDS);
// noise[b] staged to LDS via coalesced float4 then conflict-free stride-17 reads.
__global__ __launch_bounds__(512) void k_weights(const float* __restrict__ amp,
                                                 const float* __restrict__ w_gate,
                                                 const float* __restrict__ w_noise,
                                                 const float* __restrict__ noise,
                                                 const int* __restrict__ training,
                                                 const int* __restrict__ top_k,
                                                 float* __restrict__ out) {
    const int b = blockIdx.x;
    const int tid = threadIdx.x;   // o
    __shared__ float ns[NHID * NS];          // 34.8 KB
    {
        const float4* src = reinterpret_cast<const float4*>(noise + (size_t)b * NHID * NS);
        float4* dst = reinterpret_cast<float4*>(ns);
        for (int i = tid; i < NHID * NS / 4; i += 512) dst[i] = src[i];  // 2176 float4
    }
    __syncthreads();

    const float4* a4 = reinterpret_cast<const float4*>(amp + ((size_t)b * NHID + tid) * NF);
    float aC[NS], aN[NS];
#pragma unroll
    for (int s = 0; s < NS; ++s) { aC[s] = 0.f; aN[s] = 0.f; }
#pragma unroll
    for (int q = 0; q < NF / 4; ++q) {
        float4 av = a4[q];
        float a[4] = {av.x, av.y, av.z, av.w};
#pragma unroll
        for (int u = 0; u < 4; ++u) {
            const int ff = q * 4 + u;
#pragma unroll
            for (int s = 0; s < NS; ++s) {
                aC[s] = fmaf(a[u], w_gate [ff * NS + s], aC[s]);   // uniform addr -> s_load
                aN[s] = fmaf(a[u], w_noise[ff * NS + s], aN[s]);
            }
        }
    }
    const int tr = training[0];
    float vals[NS];
#pragma unroll
    for (int s = 0; s < NS; ++s) {
        float v = aC[s];
        if (tr) {
            float xx = aN[s];
            float sp = fmaxf(xx, 0.f) + log1pf(expf(-fabsf(xx)));   // stable softplus
            v += ns[tid * NS + s] * (sp + 0.01f);
        }
        vals[s] = v;
    }
#pragma unroll
    for (int s = 0; s < NS; ++s) {
#pragma unroll
        for (int off = 1; off <= 32; off <<= 1)
            vals[s] += __shfl_xor(vals[s], off);
    }
    __shared__ float red[8][NS];
    __shared__ float wfin[NS];
    const int wave = tid >> 6;
    const int lane = tid & 63;
    if (lane == 0) {
#pragma unroll
        for (int s = 0; s < NS; ++s) red[wave][s] = vals[s];
    }
    __syncthreads();
    if (tid < NS) {
        float sum = 0.f;
#pragma unroll
        for (int w = 0; w < 8; ++w) sum += red[w][tid];
        wfin[tid] = sum * (1.0f / 512.0f);
    }
    __syncthreads();
    if (tid == 0) {
        int k = top_k[0];
        if (k < 1) k = 1;
        if (k > NS) k = NS;
        float w[NS];
#pragma unroll
        for (int s = 0; s < NS; ++s) w[s] = wfin[s];
        float tv[NS];
        int   ti[NS];
        int used = 0;
        for (int kk = 0; kk < k; ++kk) {
            float best = -INFINITY;
            int bi = 0;
#pragma unroll
            for (int s = 0; s < NS; ++s) {
                if (!((used >> s) & 1) && w[s] > best) { best = w[s]; bi = s; } // '>' => lowest idx on tie
            }
            tv[kk] = best; ti[kk] = bi; used |= (1 << bi);
        }
        const float m = tv[0];
        float sum = 0.f;
        for (int kk = 0; kk < k; ++kk) { tv[kk] = expf(tv[kk] - m); sum += tv[kk]; }
        float outv[NS];
#pragma unroll
        for (int s = 0; s < NS; ++s) outv[s] = 0.f;
        for (int kk = 0; kk < k; ++kk) outv[ti[kk]] = tv[kk] / sum;
#pragma unroll
        for (int s = 0; s < NS; ++s) out[b * NS + s] = outv[s];
    }
}

extern "C" void kernel_launch(void* const* d_in, const int* in_sizes, int n_in,
                              void* d_out, int out_size, void* d_ws, size_t ws_size,
                              hipStream_t stream) {
    const float* x        = (const float*)d_in[0];
    const float* in_w     = (const float*)d_in[1];
    // d_in[2] = in_b: irrelevant (contributes only to the dropped DC bin)
    const float* w_gate   = (const float*)d_in[3];
    const float* w_noise  = (const float*)d_in[4];
    const float* noise    = (const float*)d_in[5];
    const int*   training = (const int*)d_in[6];
    const int*   top_k    = (const int*)d_in[7];
    float* out = (float*)d_out;

    float* ws  = (float*)d_ws;
    float*  xm = ws;                                     // 16*96*192 floats = 294912
    float2* PT = (float2*)(xm + (size_t)NB * NT * NJ);   // 16*192*48 float2 = 147456
    float* amp = (float*)(PT + (size_t)NB * NJ * NF);    // 16*512*48 floats = 393216

    k_mean   <<<NB * NT * NC, 256, 0, stream>>>(x, xm);
    k_dft    <<<NB * NF,      192, 0, stream>>>(xm, PT);
    k_amp    <<<NB * 16,      192, 0, stream>>>(in_w, PT, amp);
    k_weights<<<NB,           512, 0, stream>>>(amp, w_gate, w_noise, noise, training, top_k, out);
}

// Round 6
// 458.156 us; speedup vs baseline: 1.0608x; 1.0608x over previous
//
#include <hip/hip_runtime.h>
#include <hip/hip_bf16.h>
#include <math.h>

#define NB 16
#define NT 96
#define NC 3
#define ND 64
#define NJ 192   // C*D
#define NHID 512
#define NF 48
#define NS 17

// ---------------- K1: mean over (H,W): x[B,T,C,16,16,64] -> xm[B,T,192] ----------------
// One block per (b,t,c): 4096 float4, 256 threads x 16 iters, coalesced. BW-bound.
__global__ __launch_bounds__(256) void k_mean(const float* __restrict__ x,
                                              float* __restrict__ xm) {
    const int blk = blockIdx.x;                 // (b*NT+t)*NC + c
    const int tid = threadIdx.x;
    const float4* xin = reinterpret_cast<const float4*>(x) + (size_t)blk * 4096;
    float4 acc = make_float4(0.f, 0.f, 0.f, 0.f);
#pragma unroll
    for (int k = 0; k < 16; ++k) {
        float4 v = xin[k * 256 + tid];
        acc.x += v.x; acc.y += v.y; acc.z += v.z; acc.w += v.w;
    }
    __shared__ float4 sums[256];
    sums[tid] = acc;
    __syncthreads();
    if (tid < 16) {
        float4 tot = make_float4(0.f, 0.f, 0.f, 0.f);
#pragma unroll
        for (int g = 0; g < 16; ++g) {
            float4 v = sums[g * 16 + tid];
            tot.x += v.x; tot.y += v.y; tot.z += v.z; tot.w += v.w;
        }
        const float s = 1.0f / 256.0f;
        tot.x *= s; tot.y *= s; tot.z *= s; tot.w *= s;
        const int c  = blk % NC;
        const int bt = blk / NC;
        float4* out = reinterpret_cast<float4*>(xm + (size_t)bt * NJ + c * ND);
        out[tid] = tot;
    }
}

// ---------------- K2: DFT with incremental rotation, output PT[b][j][f] = float2{re,im} ----
// PT[b,j,f] = (1/sqrt96) * sum_t xm[b,t,j] e^{-i 2pi (f+1) t/96}
// Block per (b, jc of 4 j); 192 threads = (jj 0..3) x (f 0..47). 1 sincosf/thread.
__global__ __launch_bounds__(192) void k_dft(const float* __restrict__ xm,
                                             float2* __restrict__ PT) {
    const int b  = blockIdx.x / NF;
    const int jc = blockIdx.x % NF;
    const int tid = threadIdx.x;
    const int f  = tid % 48;
    const int jj = tid / 48;
    __shared__ float xs[NT][4];
    for (int i = tid; i < NT * 4; i += 192) {
        const int t = i >> 2, j4 = i & 3;
        xs[t][j4] = xm[((size_t)b * NT + t) * NJ + jc * 4 + j4];
    }
    __syncthreads();
    const float th = (2.0f * 3.14159265358979323846f / 96.0f) * (float)(f + 1);
    float s0, c0;
    sincosf(th, &s0, &c0);
    float c = 1.f, s = 0.f;        // rotates through cos/sin((f+1)*t*2pi/96)
    float re = 0.f, im = 0.f;
    for (int t = 0; t < NT; ++t) {
        const float xv = xs[t][jj];
        re = fmaf(xv, c, re);
        im = fmaf(xv, s, im);
        const float cn = c * c0 - s * s0;
        s = s * c0 + c * s0;       // uses old c (cn not yet committed)
        c = cn;
    }
    const float inv = 0.1020620726159657f;  // 1/sqrt(96)
    const int j = jc * 4 + jj;
    PT[((size_t)b * NJ + j) * NF + f] = make_float2(re * inv, -im * inv);  // coalesced 8B/lane
}

// ---------------- K3: amp[b,o,f] = |sum_j in_w[o,j] * PT[b,j,f]| ----------------
// Grid 256 = (b 16) x (ot 16, O-tile 32). 192 thr: og=tid&7 (4 o each), fg=tid>>3 (2 f each).
// Per j: 1 ds_read_b128 of wcT (16B-aligned) + 1 coalesced/broadcast global float4 of PT
// + 16 FMA  ->  VALU-bound, full chip.
__global__ __launch_bounds__(192) void k_amp(const float* __restrict__ in_w,
                                             const float2* __restrict__ PT,
                                             float* __restrict__ amp) {
    const int b  = blockIdx.x >> 4;
    const int ot = blockIdx.x & 15;
    const int tid = threadIdx.x;
    const int og = tid & 7;            // o = ot*32 + og*4 + r
    const int fg = tid >> 3;           // f = fg*2 + {0,1}
    __shared__ float wcT[NJ][36];      // [j][o_local], row = 144 B (16B-aligned), 27.6 KB
    for (int k = 0; k < 32; ++k) {     // stage in_w transposed; global read coalesced (j = tid)
        wcT[tid][k] = in_w[(size_t)(ot * 32 + k) * NJ + tid];
    }
    __syncthreads();
    const float2* ptb = PT + (size_t)b * NJ * NF;
    float re0[4] = {0.f,0.f,0.f,0.f}, im0[4] = {0.f,0.f,0.f,0.f};
    float re1[4] = {0.f,0.f,0.f,0.f}, im1[4] = {0.f,0.f,0.f,0.f};
#pragma unroll 4
    for (int j = 0; j < NJ; ++j) {
        const float4 p  = *reinterpret_cast<const float4*>(&ptb[(size_t)j * NF + fg * 2]);
        const float4 w4 = *reinterpret_cast<const float4*>(&wcT[j][og * 4]);
        const float wv[4] = {w4.x, w4.y, w4.z, w4.w};
#pragma unroll
        for (int r = 0; r < 4; ++r) {
            re0[r] = fmaf(wv[r], p.x, re0[r]);
            im0[r] = fmaf(wv[r], p.y, im0[r]);
            re1[r] = fmaf(wv[r], p.z, re1[r]);
            im1[r] = fmaf(wv[r], p.w, im1[r]);
        }
    }
#pragma unroll
    for (int r = 0; r < 4; ++r) {
        const int o = ot * 32 + og * 4 + r;
        float2 a;
        a.x = sqrtf(re0[r] * re0[r] + im0[r] * im0[r]);
        a.y = sqrtf(re1[r] * re1[r] + im1[r] * im1[r]);
        *reinterpret_cast<float2*>(&amp[((size_t)b * NHID + o) * NF + fg * 2]) = a;
    }
}

// ---------------- K4: weights + top-k fused. Block per b, 512 threads (one per o). ----
// wg/wn staged to LDS (stride-20 pad -> vectorized broadcast ds_read; PROVEN in round 4);
// noise[b] staged to LDS via coalesced float4 then conflict-free stride-17 reads.
__global__ __launch_bounds__(512) void k_weights(const float* __restrict__ amp,
                                                 const float* __restrict__ w_gate,
                                                 const float* __restrict__ w_noise,
                                                 const float* __restrict__ noise,
                                                 const int* __restrict__ training,
                                                 const int* __restrict__ top_k,
                                                 float* __restrict__ out) {
    const int b = blockIdx.x;
    const int tid = threadIdx.x;   // o
    __shared__ float wg[NF * 20];            // stride-20: 80 B rows, 16B-aligned
    __shared__ float wn[NF * 20];
    __shared__ float ns[NHID * NS];          // 34.8 KB
    for (int i = tid; i < NF * 20; i += 512) {
        const int ff = i / 20, s = i % 20;
        wg[i] = (s < NS) ? w_gate[ff * NS + s] : 0.f;
        wn[i] = (s < NS) ? w_noise[ff * NS + s] : 0.f;
    }
    {
        const float4* src = reinterpret_cast<const float4*>(noise + (size_t)b * NHID * NS);
        float4* dst = reinterpret_cast<float4*>(ns);
        for (int i = tid; i < NHID * NS / 4; i += 512) dst[i] = src[i];  // 2176 float4
    }
    __syncthreads();

    const float4* a4 = reinterpret_cast<const float4*>(amp + ((size_t)b * NHID + tid) * NF);
    float aC[NS], aN[NS];
#pragma unroll
    for (int s = 0; s < NS; ++s) { aC[s] = 0.f; aN[s] = 0.f; }
#pragma unroll
    for (int q = 0; q < NF / 4; ++q) {
        float4 av = a4[q];
        float a[4] = {av.x, av.y, av.z, av.w};
#pragma unroll
        for (int u = 0; u < 4; ++u) {
            const int ff = q * 4 + u;
#pragma unroll
            for (int s = 0; s < NS; ++s) {
                aC[s] = fmaf(a[u], wg[ff * 20 + s], aC[s]);
                aN[s] = fmaf(a[u], wn[ff * 20 + s], aN[s]);
            }
        }
    }
    const int tr = training[0];
    float vals[NS];
#pragma unroll
    for (int s = 0; s < NS; ++s) {
        float v = aC[s];
        if (tr) {
            float xx = aN[s];
            float sp = fmaxf(xx, 0.f) + log1pf(expf(-fabsf(xx)));   // stable softplus
            v += ns[tid * NS + s] * (sp + 0.01f);
        }
        vals[s] = v;
    }
#pragma unroll
    for (int s = 0; s < NS; ++s) {
#pragma unroll
        for (int off = 1; off <= 32; off <<= 1)
            vals[s] += __shfl_xor(vals[s], off);
    }
    __shared__ float red[8][NS];
    __shared__ float wfin[NS];
    const int wave = tid >> 6;
    const int lane = tid & 63;
    if (lane == 0) {
#pragma unroll
        for (int s = 0; s < NS; ++s) red[wave][s] = vals[s];
    }
    __syncthreads();
    if (tid < NS) {
        float sum = 0.f;
#pragma unroll
        for (int w = 0; w < 8; ++w) sum += red[w][tid];
        wfin[tid] = sum * (1.0f / 512.0f);
    }
    __syncthreads();
    if (tid == 0) {
        int k = top_k[0];
        if (k < 1) k = 1;
        if (k > NS) k = NS;
        float w[NS];
#pragma unroll
        for (int s = 0; s < NS; ++s) w[s] = wfin[s];
        float tv[NS];
        int   ti[NS];
        int used = 0;
        for (int kk = 0; kk < k; ++kk) {
            float best = -INFINITY;
            int bi = 0;
#pragma unroll
            for (int s = 0; s < NS; ++s) {
                if (!((used >> s) & 1) && w[s] > best) { best = w[s]; bi = s; } // '>' => lowest idx on tie
            }
            tv[kk] = best; ti[kk] = bi; used |= (1 << bi);
        }
        const float m = tv[0];
        float sum = 0.f;
        for (int kk = 0; kk < k; ++kk) { tv[kk] = expf(tv[kk] - m); sum += tv[kk]; }
        float outv[NS];
#pragma unroll
        for (int s = 0; s < NS; ++s) outv[s] = 0.f;
        for (int kk = 0; kk < k; ++kk) outv[ti[kk]] = tv[kk] / sum;
#pragma unroll
        for (int s = 0; s < NS; ++s) out[b * NS + s] = outv[s];
    }
}

extern "C" void kernel_launch(void* const* d_in, const int* in_sizes, int n_in,
                              void* d_out, int out_size, void* d_ws, size_t ws_size,
                              hipStream_t stream) {
    const float* x        = (const float*)d_in[0];
    const float* in_w     = (const float*)d_in[1];
    // d_in[2] = in_b: irrelevant (contributes only to the dropped DC bin)
    const float* w_gate   = (const float*)d_in[3];
    const float* w_noise  = (const float*)d_in[4];
    const float* noise    = (const float*)d_in[5];
    const int*   training = (const int*)d_in[6];
    const int*   top_k    = (const int*)d_in[7];
    float* out = (float*)d_out;

    float* ws  = (float*)d_ws;
    float*  xm = ws;                                     // 16*96*192 floats = 294912
    float2* PT = (float2*)(xm + (size_t)NB * NT * NJ);   // 16*192*48 float2 = 147456
    float* amp = (float*)(PT + (size_t)NB * NJ * NF);    // 16*512*48 floats = 393216

    k_mean   <<<NB * NT * NC, 256, 0, stream>>>(x, xm);
    k_dft    <<<NB * NF,      192, 0, stream>>>(xm, PT);
    k_amp    <<<NB * 16,      192, 0, stream>>>(in_w, PT, amp);
    k_weights<<<NB,           512, 0, stream>>>(amp, w_gate, w_noise, noise, training, top_k, out);
}

// Round 7
// 95.815 us; speedup vs baseline: 5.0724x; 4.7817x over previous
//
#include <hip/hip_runtime.h>
#include <hip/hip_bf16.h>
#include <math.h>

#define NB 16
#define NT 96
#define NC 3
#define ND 64
#define NJ 192   // C*D
#define NHID 512
#define NF 48
#define NS 17

// ---------------- K1: mean over (H,W): x[B,T,C,16,16,64] -> xm[B,T,192] ----------------
// One block per (b,t,c): 4096 float4, 256 threads x 16 iters, coalesced. BW-bound.
__global__ __launch_bounds__(256) void k_mean(const float* __restrict__ x,
                                              float* __restrict__ xm) {
    const int blk = blockIdx.x;                 // (b*NT+t)*NC + c
    const int tid = threadIdx.x;
    const float4* xin = reinterpret_cast<const float4*>(x) + (size_t)blk * 4096;
    float4 acc = make_float4(0.f, 0.f, 0.f, 0.f);
#pragma unroll
    for (int k = 0; k < 16; ++k) {
        float4 v = xin[k * 256 + tid];
        acc.x += v.x; acc.y += v.y; acc.z += v.z; acc.w += v.w;
    }
    __shared__ float4 sums[256];
    sums[tid] = acc;
    __syncthreads();
    if (tid < 16) {
        float4 tot = make_float4(0.f, 0.f, 0.f, 0.f);
#pragma unroll
        for (int g = 0; g < 16; ++g) {
            float4 v = sums[g * 16 + tid];
            tot.x += v.x; tot.y += v.y; tot.z += v.z; tot.w += v.w;
        }
        const float s = 1.0f / 256.0f;
        tot.x *= s; tot.y *= s; tot.z *= s; tot.w *= s;
        const int c  = blk % NC;
        const int bt = blk / NC;
        float4* out = reinterpret_cast<float4*>(xm + (size_t)bt * NJ + c * ND);
        out[tid] = tot;
    }
}

// ---------------- K2: DFT with incremental rotation, output PT[b][j][f] = float2{re,im} ----
// PT[b,j,f] = (1/sqrt96) * sum_t xm[b,t,j] e^{-i 2pi (f+1) t/96}
// Block per (b, jc of 4 j); 192 threads = (jj 0..3) x (f 0..47). 1 sincosf/thread.
__global__ __launch_bounds__(192) void k_dft(const float* __restrict__ xm,
                                             float2* __restrict__ PT) {
    const int b  = blockIdx.x / NF;
    const int jc = blockIdx.x % NF;
    const int tid = threadIdx.x;
    const int f  = tid % 48;
    const int jj = tid / 48;
    __shared__ float xs[NT][4];
    for (int i = tid; i < NT * 4; i += 192) {
        const int t = i >> 2, j4 = i & 3;
        xs[t][j4] = xm[((size_t)b * NT + t) * NJ + jc * 4 + j4];
    }
    __syncthreads();
    const float th = (2.0f * 3.14159265358979323846f / 96.0f) * (float)(f + 1);
    float s0, c0;
    sincosf(th, &s0, &c0);
    float c = 1.f, s = 0.f;        // rotates through cos/sin((f+1)*t*2pi/96)
    float re = 0.f, im = 0.f;
    for (int t = 0; t < NT; ++t) {
        const float xv = xs[t][jj];
        re = fmaf(xv, c, re);
        im = fmaf(xv, s, im);
        const float cn = c * c0 - s * s0;
        s = s * c0 + c * s0;       // uses old c (cn not yet committed)
        c = cn;
    }
    const float inv = 0.1020620726159657f;  // 1/sqrt(96)
    const int j = jc * 4 + jj;
    PT[((size_t)b * NJ + j) * NF + f] = make_float2(re * inv, -im * inv);  // coalesced 8B/lane
}

// ---------------- K3: amp[b,o,f] = |sum_j in_w[o,j] * PT[b,j,f]| ----------------
// Grid 256 = (b 16) x (ot 16, O-tile 32). 192 thr: og=tid&7 (4 o each), fg=tid>>3 (2 f each).
__global__ __launch_bounds__(192) void k_amp(const float* __restrict__ in_w,
                                             const float2* __restrict__ PT,
                                             float* __restrict__ amp) {
    const int b  = blockIdx.x >> 4;
    const int ot = blockIdx.x & 15;
    const int tid = threadIdx.x;
    const int og = tid & 7;            // o = ot*32 + og*4 + r
    const int fg = tid >> 3;           // f = fg*2 + {0,1}
    __shared__ float wcT[NJ][36];      // [j][o_local], row = 144 B (16B-aligned), 27.6 KB
    for (int k = 0; k < 32; ++k) {     // stage in_w transposed; global read coalesced (j = tid)
        wcT[tid][k] = in_w[(size_t)(ot * 32 + k) * NJ + tid];
    }
    __syncthreads();
    const float2* ptb = PT + (size_t)b * NJ * NF;
    float re0[4] = {0.f,0.f,0.f,0.f}, im0[4] = {0.f,0.f,0.f,0.f};
    float re1[4] = {0.f,0.f,0.f,0.f}, im1[4] = {0.f,0.f,0.f,0.f};
#pragma unroll 4
    for (int j = 0; j < NJ; ++j) {
        const float4 p  = *reinterpret_cast<const float4*>(&ptb[(size_t)j * NF + fg * 2]);
        const float4 w4 = *reinterpret_cast<const float4*>(&wcT[j][og * 4]);
        const float wv[4] = {w4.x, w4.y, w4.z, w4.w};
#pragma unroll
        for (int r = 0; r < 4; ++r) {
            re0[r] = fmaf(wv[r], p.x, re0[r]);
            im0[r] = fmaf(wv[r], p.y, im0[r]);
            re1[r] = fmaf(wv[r], p.z, re1[r]);
            im1[r] = fmaf(wv[r], p.w, im1[r]);
        }
    }
#pragma unroll
    for (int r = 0; r < 4; ++r) {
        const int o = ot * 32 + og * 4 + r;
        float2 a;
        a.x = sqrtf(re0[r] * re0[r] + im0[r] * im0[r]);
        a.y = sqrtf(re1[r] * re1[r] + im1[r] * im1[r]);
        *reinterpret_cast<float2*>(&amp[((size_t)b * NHID + o) * NF + fg * 2]) = a;
    }
}

// ---------------- K4: weights + top-k fused. Block per b, 512 threads (one per o). ----
// ROUND-4 PROVEN CODEGEN: rolled q loop (NO unroll pragma -> no spill), wg/wn in
// stride-20 LDS (vectorized broadcast ds_read), noise read direct from global.
__global__ __launch_bounds__(512) void k_weights(const float* __restrict__ amp,
                                                 const float* __restrict__ w_gate,
                                                 const float* __restrict__ w_noise,
                                                 const float* __restrict__ noise,
                                                 const int* __restrict__ training,
                                                 const int* __restrict__ top_k,
                                                 float* __restrict__ out) {
    const int b = blockIdx.x;
    const int tid = threadIdx.x;   // o
    __shared__ float wg[NF * 20];            // stride-20: 80 B rows, 16B-aligned
    __shared__ float wn[NF * 20];
    for (int i = tid; i < NF * 20; i += 512) {
        const int ff = i / 20, s = i % 20;
        wg[i] = (s < NS) ? w_gate[ff * NS + s] : 0.f;
        wn[i] = (s < NS) ? w_noise[ff * NS + s] : 0.f;
    }
    __syncthreads();

    const float4* a4 = reinterpret_cast<const float4*>(amp + ((size_t)b * NHID + tid) * NF);
    float aC[NS], aN[NS];
#pragma unroll
    for (int s = 0; s < NS; ++s) { aC[s] = 0.f; aN[s] = 0.f; }
    for (int q = 0; q < NF / 4; ++q) {       // ROLLED: 12 iters, keeps pressure at ~34 live floats
        float4 av = a4[q];
        float a[4] = {av.x, av.y, av.z, av.w};
#pragma unroll
        for (int u = 0; u < 4; ++u) {
            const int ff = q * 4 + u;
#pragma unroll
            for (int s = 0; s < NS; ++s) {
                aC[s] = fmaf(a[u], wg[ff * 20 + s], aC[s]);
                aN[s] = fmaf(a[u], wn[ff * 20 + s], aN[s]);
            }
        }
    }
    const int tr = training[0];
    const float* nrow = noise + ((size_t)b * NHID + tid) * NS;
#pragma unroll
    for (int s = 0; s < NS; ++s) {
        if (tr) {
            float xx = aN[s];
            float sp = fmaxf(xx, 0.f) + log1pf(expf(-fabsf(xx)));   // stable softplus
            aC[s] += nrow[s] * (sp + 0.01f);
        }
    }
#pragma unroll
    for (int s = 0; s < NS; ++s) {
#pragma unroll
        for (int off = 1; off <= 32; off <<= 1)
            aC[s] += __shfl_xor(aC[s], off);
    }
    __shared__ float red[8][NS];
    __shared__ float wfin[NS];
    const int wave = tid >> 6;
    const int lane = tid & 63;
    if (lane == 0) {
#pragma unroll
        for (int s = 0; s < NS; ++s) red[wave][s] = aC[s];
    }
    __syncthreads();
    if (tid < NS) {
        float sum = 0.f;
#pragma unroll
        for (int w = 0; w < 8; ++w) sum += red[w][tid];
        wfin[tid] = sum * (1.0f / 512.0f);
    }
    __syncthreads();
    if (tid == 0) {
        int k = top_k[0];
        if (k < 1) k = 1;
        if (k > NS) k = NS;
        float w[NS];
#pragma unroll
        for (int s = 0; s < NS; ++s) w[s] = wfin[s];
        float tv[NS];
        int   ti[NS];
        int used = 0;
        for (int kk = 0; kk < k; ++kk) {
            float best = -INFINITY;
            int bi = 0;
#pragma unroll
            for (int s = 0; s < NS; ++s) {
                if (!((used >> s) & 1) && w[s] > best) { best = w[s]; bi = s; } // '>' => lowest idx on tie
            }
            tv[kk] = best; ti[kk] = bi; used |= (1 << bi);
        }
        const float m = tv[0];
        float sum = 0.f;
        for (int kk = 0; kk < k; ++kk) { tv[kk] = expf(tv[kk] - m); sum += tv[kk]; }
        float outv[NS];
#pragma unroll
        for (int s = 0; s < NS; ++s) outv[s] = 0.f;
        for (int kk = 0; kk < k; ++kk) outv[ti[kk]] = tv[kk] / sum;
#pragma unroll
        for (int s = 0; s < NS; ++s) out[b * NS + s] = outv[s];
    }
}

extern "C" void kernel_launch(void* const* d_in, const int* in_sizes, int n_in,
                              void* d_out, int out_size, void* d_ws, size_t ws_size,
                              hipStream_t stream) {
    const float* x        = (const float*)d_in[0];
    const float* in_w     = (const float*)d_in[1];
    // d_in[2] = in_b: irrelevant (contributes only to the dropped DC bin)
    const float* w_gate   = (const float*)d_in[3];
    const float* w_noise  = (const float*)d_in[4];
    const float* noise    = (const float*)d_in[5];
    const int*   training = (const int*)d_in[6];
    const int*   top_k    = (const int*)d_in[7];
    float* out = (float*)d_out;

    float* ws  = (float*)d_ws;
    float*  xm = ws;                                     // 16*96*192 floats = 294912
    float2* PT = (float2*)(xm + (size_t)NB * NT * NJ);   // 16*192*48 float2 = 147456
    float* amp = (float*)(PT + (size_t)NB * NJ * NF);    // 16*512*48 floats = 393216

    k_mean   <<<NB * NT * NC, 256, 0, stream>>>(x, xm);
    k_dft    <<<NB * NF,      192, 0, stream>>>(xm, PT);
    k_amp    <<<NB * 16,      192, 0, stream>>>(in_w, PT, amp);
    k_weights<<<NB,           512, 0, stream>>>(amp, w_gate, w_noise, noise, training, top_k, out);
}

// Round 8
// 84.269 us; speedup vs baseline: 5.7673x; 1.1370x over previous
//
#include <hip/hip_runtime.h>
#include <hip/hip_bf16.h>
#include <math.h>

#define NB 16
#define NT 96
#define NC 3
#define ND 64
#define NJ 192   // C*D
#define NHID 512
#define NF 48
#define NS 17

// ---------------- K1: mean over (H,W): x[B,T,C,16,16,64] -> xm[B,T,192] ----------------
// One block per (b,t,c): 4096 float4, 256 threads x 16 iters, coalesced. BW-bound. PROVEN.
__global__ __launch_bounds__(256) void k_mean(const float* __restrict__ x,
                                              float* __restrict__ xm) {
    const int blk = blockIdx.x;                 // (b*NT+t)*NC + c
    const int tid = threadIdx.x;
    const float4* xin = reinterpret_cast<const float4*>(x) + (size_t)blk * 4096;
    float4 acc = make_float4(0.f, 0.f, 0.f, 0.f);
#pragma unroll
    for (int k = 0; k < 16; ++k) {
        float4 v = xin[k * 256 + tid];
        acc.x += v.x; acc.y += v.y; acc.z += v.z; acc.w += v.w;
    }
    __shared__ float4 sums[256];
    sums[tid] = acc;
    __syncthreads();
    if (tid < 16) {
        float4 tot = make_float4(0.f, 0.f, 0.f, 0.f);
#pragma unroll
        for (int g = 0; g < 16; ++g) {
            float4 v = sums[g * 16 + tid];
            tot.x += v.x; tot.y += v.y; tot.z += v.z; tot.w += v.w;
        }
        const float s = 1.0f / 256.0f;
        tot.x *= s; tot.y *= s; tot.z *= s; tot.w *= s;
        const int c  = blk % NC;
        const int bt = blk / NC;
        float4* out = reinterpret_cast<float4*>(xm + (size_t)bt * NJ + c * ND);
        out[tid] = tot;
    }
}

// ---------------- K2: DFT with incremental rotation, output PT[b][j][f] = float2{re,im} ----
// Block per (b, jc of 4 j); 192 threads = (jj 0..3) x (f 0..47). 1 sincosf/thread. PROVEN.
__global__ __launch_bounds__(192) void k_dft(const float* __restrict__ xm,
                                             float2* __restrict__ PT) {
    const int b  = blockIdx.x / NF;
    const int jc = blockIdx.x % NF;
    const int tid = threadIdx.x;
    const int f  = tid % 48;
    const int jj = tid / 48;
    __shared__ float xs[NT][4];
    for (int i = tid; i < NT * 4; i += 192) {
        const int t = i >> 2, j4 = i & 3;
        xs[t][j4] = xm[((size_t)b * NT + t) * NJ + jc * 4 + j4];
    }
    __syncthreads();
    const float th = (2.0f * 3.14159265358979323846f / 96.0f) * (float)(f + 1);
    float s0, c0;
    sincosf(th, &s0, &c0);
    float c = 1.f, s = 0.f;
    float re = 0.f, im = 0.f;
    for (int t = 0; t < NT; ++t) {
        const float xv = xs[t][jj];
        re = fmaf(xv, c, re);
        im = fmaf(xv, s, im);
        const float cn = c * c0 - s * s0;
        s = s * c0 + c * s0;
        c = cn;
    }
    const float inv = 0.1020620726159657f;  // 1/sqrt(96)
    const int j = jc * 4 + jj;
    PT[((size_t)b * NJ + j) * NF + f] = make_float2(re * inv, -im * inv);
}

// ---------------- K3: fused amp + s-contraction -> per-(b,ot) partials ----------------
// Grid 256 = (b 16) x (ot 16, O-tile 32). 192 thr.
// Phase 1 (= proven round-7 k_amp): og=tid&7 (4 o), fg=tid>>3 (2 f); amp tile -> LDS.
// Phase 2: ol=tid&31 (o), sg=tid>>5 (3 s each); gate/noise contraction over f,
//          softplus + noise, shuffle-reduce over o -> wpart[b][ot][18].
__global__ __launch_bounds__(192) void k_ampw(const float* __restrict__ in_w,
                                              const float2* __restrict__ PT,
                                              const float* __restrict__ w_gate,
                                              const float* __restrict__ w_noise,
                                              const float* __restrict__ noise,
                                              const int* __restrict__ training,
                                              float* __restrict__ wpart) {
    const int b  = blockIdx.x >> 4;
    const int ot = blockIdx.x & 15;
    const int tid = threadIdx.x;
    __shared__ float wcT[NJ][36];      // [j][o_local] 27.6 KB, rows 144 B (16B-aligned)
    __shared__ float ampL[32][50];     // [o_local][f], stride 50 -> float2-aligned, 6.4 KB
    __shared__ float wg[NF * 20];      // stride-20 pad (PROVEN)
    __shared__ float wn[NF * 20];
    for (int k = 0; k < 32; ++k)       // stage in_w transposed; coalesced (j = tid)
        wcT[tid][k] = in_w[(size_t)(ot * 32 + k) * NJ + tid];
    for (int i = tid; i < NF * 20; i += 192) {
        const int ff = i / 20, s = i % 20;
        wg[i] = (s < NS) ? w_gate[ff * NS + s] : 0.f;
        wn[i] = (s < NS) ? w_noise[ff * NS + s] : 0.f;
    }
    __syncthreads();

    // ---- phase 1: amp tile (proven codegen) ----
    {
        const int og = tid & 7;
        const int fg = tid >> 3;
        const float2* ptb = PT + (size_t)b * NJ * NF;
        float re0[4] = {0.f,0.f,0.f,0.f}, im0[4] = {0.f,0.f,0.f,0.f};
        float re1[4] = {0.f,0.f,0.f,0.f}, im1[4] = {0.f,0.f,0.f,0.f};
#pragma unroll 4
        for (int j = 0; j < NJ; ++j) {
            const float4 p  = *reinterpret_cast<const float4*>(&ptb[(size_t)j * NF + fg * 2]);
            const float4 w4 = *reinterpret_cast<const float4*>(&wcT[j][og * 4]);
            const float wv[4] = {w4.x, w4.y, w4.z, w4.w};
#pragma unroll
            for (int r = 0; r < 4; ++r) {
                re0[r] = fmaf(wv[r], p.x, re0[r]);
                im0[r] = fmaf(wv[r], p.y, im0[r]);
                re1[r] = fmaf(wv[r], p.z, re1[r]);
                im1[r] = fmaf(wv[r], p.w, im1[r]);
            }
        }
#pragma unroll
        for (int r = 0; r < 4; ++r) {
            float2 a;
            a.x = sqrtf(re0[r] * re0[r] + im0[r] * im0[r]);
            a.y = sqrtf(re1[r] * re1[r] + im1[r] * im1[r]);
            *reinterpret_cast<float2*>(&ampL[og * 4 + r][fg * 2]) = a;
        }
    }
    __syncthreads();

    // ---- phase 2: contraction + softplus + noise, reduce over o ----
    const int ol = tid & 31;           // o_local
    const int sg = tid >> 5;           // 0..5, s = sg*3 + k
    float aC[3] = {0.f, 0.f, 0.f};
    float aN[3] = {0.f, 0.f, 0.f};
    for (int f = 0; f < NF; ++f) {     // rolled: low pressure (round-6 lesson)
        const float a = ampL[ol][f];
#pragma unroll
        for (int k = 0; k < 3; ++k) {
            aC[k] = fmaf(a, wg[f * 20 + sg * 3 + k], aC[k]);
            aN[k] = fmaf(a, wn[f * 20 + sg * 3 + k], aN[k]);
        }
    }
    const int tr = training[0];
    const int o = ot * 32 + ol;
    float v[3];
#pragma unroll
    for (int k = 0; k < 3; ++k) {
        const int s = sg * 3 + k;
        float val = aC[k];
        if (tr && s < NS) {
            const float xx = aN[k];
            const float sp = fmaxf(xx, 0.f) + log1pf(expf(-fabsf(xx)));   // stable softplus
            val += noise[((size_t)b * NHID + o) * NS + s] * (sp + 0.01f);
        }
        v[k] = val;
    }
#pragma unroll
    for (int k = 0; k < 3; ++k) {
#pragma unroll
        for (int off = 1; off <= 16; off <<= 1)
            v[k] += __shfl_xor(v[k], off);     // reduce over ol (32-aligned lane groups)
    }
    if (ol == 0) {
        float* wp = wpart + ((size_t)(b * 16 + ot)) * 18;
#pragma unroll
        for (int k = 0; k < 3; ++k) {
            const int s = sg * 3 + k;
            if (s < NS) wp[s] = v[k];
        }
    }
}

// ---------------- K4: reduce 16 ot-partials per b, mean, top-k, softmax, scatter ----
__global__ __launch_bounds__(256) void k_final(const float* __restrict__ wpart,
                                               const int* __restrict__ top_k,
                                               float* __restrict__ out) {
    const int tid = threadIdx.x;
    const int b  = tid >> 4;
    const int ot = tid & 15;
    float acc[NS];
    const float* wp = wpart + ((size_t)(b * 16 + ot)) * 18;
#pragma unroll
    for (int s = 0; s < NS; ++s) acc[s] = wp[s];
#pragma unroll
    for (int s = 0; s < NS; ++s) {
#pragma unroll
        for (int off = 1; off <= 8; off <<= 1)
            acc[s] += __shfl_xor(acc[s], off);   // reduce over ot (16-aligned lane groups)
    }
    __shared__ float wf[NB][NS];
    if (ot == 0) {
#pragma unroll
        for (int s = 0; s < NS; ++s) wf[b][s] = acc[s] * (1.0f / 512.0f);
    }
    __syncthreads();
    if (tid < NB) {
        int k = top_k[0];
        if (k < 1) k = 1;
        if (k > NS) k = NS;
        float w[NS];
#pragma unroll
        for (int s = 0; s < NS; ++s) w[s] = wf[tid][s];
        float tv[NS];
        int   ti[NS];
        int used = 0;
        for (int kk = 0; kk < k; ++kk) {
            float best = -INFINITY;
            int bi = 0;
#pragma unroll
            for (int s = 0; s < NS; ++s) {
                if (!((used >> s) & 1) && w[s] > best) { best = w[s]; bi = s; } // '>' => lowest idx on tie
            }
            tv[kk] = best; ti[kk] = bi; used |= (1 << bi);
        }
        const float m = tv[0];
        float sum = 0.f;
        for (int kk = 0; kk < k; ++kk) { tv[kk] = expf(tv[kk] - m); sum += tv[kk]; }
        float outv[NS];
#pragma unroll
        for (int s = 0; s < NS; ++s) outv[s] = 0.f;
        for (int kk = 0; kk < k; ++kk) outv[ti[kk]] = tv[kk] / sum;
#pragma unroll
        for (int s = 0; s < NS; ++s) out[tid * NS + s] = outv[s];
    }
}

extern "C" void kernel_launch(void* const* d_in, const int* in_sizes, int n_in,
                              void* d_out, int out_size, void* d_ws, size_t ws_size,
                              hipStream_t stream) {
    const float* x        = (const float*)d_in[0];
    const float* in_w     = (const float*)d_in[1];
    // d_in[2] = in_b: irrelevant (contributes only to the dropped DC bin)
    const float* w_gate   = (const float*)d_in[3];
    const float* w_noise  = (const float*)d_in[4];
    const float* noise    = (const float*)d_in[5];
    const int*   training = (const int*)d_in[6];
    const int*   top_k    = (const int*)d_in[7];
    float* out = (float*)d_out;

    float* ws    = (float*)d_ws;
    float*  xm   = ws;                                    // 16*96*192 floats = 294912
    float2* PT   = (float2*)(xm + (size_t)NB * NT * NJ);  // 16*192*48 float2 = 147456
    float* wpart = (float*)(PT + (size_t)NB * NJ * NF);   // 16*16*18 = 4608 floats

    k_mean <<<NB * NT * NC, 256, 0, stream>>>(x, xm);
    k_dft  <<<NB * NF,      192, 0, stream>>>(xm, PT);
    k_ampw <<<NB * 16,      192, 0, stream>>>(in_w, PT, w_gate, w_noise, noise, training, wpart);
    k_final<<<1,            256, 0, stream>>>(wpart, top_k, out);
}

// Round 9
// 80.254 us; speedup vs baseline: 6.0559x; 1.0500x over previous
//
#include <hip/hip_runtime.h>
#include <hip/hip_bf16.h>
#include <math.h>

#define NB 16
#define NT 96
#define NC 3
#define ND 64
#define NJ 192   // C*D
#define NHID 512
#define NF 48
#define NS 17

// ---------------- K1: mean over (H,W): x[B,T,C,16,16,64] -> xm[B,T,192] ----------------
// One block per (b,t,c): 4096 float4, 256 threads x 16 iters, coalesced. BW-bound. PROVEN.
__global__ __launch_bounds__(256) void k_mean(const float* __restrict__ x,
                                              float* __restrict__ xm) {
    const int blk = blockIdx.x;                 // (b*NT+t)*NC + c
    const int tid = threadIdx.x;
    const float4* xin = reinterpret_cast<const float4*>(x) + (size_t)blk * 4096;
    float4 acc = make_float4(0.f, 0.f, 0.f, 0.f);
#pragma unroll
    for (int k = 0; k < 16; ++k) {
        float4 v = xin[k * 256 + tid];
        acc.x += v.x; acc.y += v.y; acc.z += v.z; acc.w += v.w;
    }
    __shared__ float4 sums[256];
    sums[tid] = acc;
    __syncthreads();
    if (tid < 16) {
        float4 tot = make_float4(0.f, 0.f, 0.f, 0.f);
#pragma unroll
        for (int g = 0; g < 16; ++g) {
            float4 v = sums[g * 16 + tid];
            tot.x += v.x; tot.y += v.y; tot.z += v.z; tot.w += v.w;
        }
        const float s = 1.0f / 256.0f;
        tot.x *= s; tot.y *= s; tot.z *= s; tot.w *= s;
        const int c  = blk % NC;
        const int bt = blk / NC;
        float4* out = reinterpret_cast<float4*>(xm + (size_t)bt * NJ + c * ND);
        out[tid] = tot;
    }
}

// ---------------- K2: DFT with incremental rotation, output PT[b][j][f] = float2{re,im} ----
// Block per (b, jc of 4 j); 192 threads = (jj 0..3) x (f 0..47). 1 sincosf/thread. PROVEN.
__global__ __launch_bounds__(192) void k_dft(const float* __restrict__ xm,
                                             float2* __restrict__ PT) {
    const int b  = blockIdx.x / NF;
    const int jc = blockIdx.x % NF;
    const int tid = threadIdx.x;
    const int f  = tid % 48;
    const int jj = tid / 48;
    __shared__ float xs[NT][4];
    for (int i = tid; i < NT * 4; i += 192) {
        const int t = i >> 2, j4 = i & 3;
        xs[t][j4] = xm[((size_t)b * NT + t) * NJ + jc * 4 + j4];
    }
    __syncthreads();
    const float th = (2.0f * 3.14159265358979323846f / 96.0f) * (float)(f + 1);
    float s0, c0;
    sincosf(th, &s0, &c0);
    float c = 1.f, s = 0.f;
    float re = 0.f, im = 0.f;
    for (int t = 0; t < NT; ++t) {
        const float xv = xs[t][jj];
        re = fmaf(xv, c, re);
        im = fmaf(xv, s, im);
        const float cn = c * c0 - s * s0;
        s = s * c0 + c * s0;
        c = cn;
    }
    const float inv = 0.1020620726159657f;  // 1/sqrt(96)
    const int j = jc * 4 + jj;
    PT[((size_t)b * NJ + j) * NF + f] = make_float2(re * inv, -im * inv);
}

// ---------------- K3: fused amp + s-contraction -> per-(b,ot) partials ----------------
// Grid 256 = (b 16) x (ot 16, O-tile 32). 384 thr (6 waves/CU -> latency hiding).
// Phase 1: f=tid%48 (coalesced PT), og=tid/48 (4 o each); 8 FMA/j; amp tile -> LDS.
// Phase 2: ol=tid&31 (o), sg=tid>>5 (2 s each); contraction over f, softplus+noise,
//          shuffle-reduce over o -> wpart[b][ot][18].
__global__ __launch_bounds__(384) void k_ampw(const float* __restrict__ in_w,
                                              const float2* __restrict__ PT,
                                              const float* __restrict__ w_gate,
                                              const float* __restrict__ w_noise,
                                              const float* __restrict__ noise,
                                              const int* __restrict__ training,
                                              float* __restrict__ wpart) {
    const int b  = blockIdx.x >> 4;
    const int ot = blockIdx.x & 15;
    const int tid = threadIdx.x;
    __shared__ float wcT[NJ][36];      // [j][o_local] 27.6 KB, rows 144 B (16B-aligned)
    __shared__ float ampL[32][50];     // [o_local][f], stride 50, 6.4 KB
    __shared__ float wg[NF * 20];      // stride-20 pad (PROVEN)
    __shared__ float wn[NF * 20];
    {   // stage in_w transposed; coalesced over j within each 192-thread half
        const int half = tid / 192;    // 0,1 -> o_local 0..15 / 16..31
        const int jt   = tid % 192;
#pragma unroll
        for (int k = 0; k < 16; ++k)
            wcT[jt][half * 16 + k] = in_w[(size_t)(ot * 32 + half * 16 + k) * NJ + jt];
    }
    for (int i = tid; i < NF * 20; i += 384) {
        const int ff = i / 20, s = i % 20;
        wg[i] = (s < NS) ? w_gate[ff * NS + s] : 0.f;
        wn[i] = (s < NS) ? w_noise[ff * NS + s] : 0.f;
    }
    __syncthreads();

    // ---- phase 1: amp tile ----
    {
        const int f  = tid % 48;       // consecutive lanes -> consecutive f (coalesced PT)
        const int og = tid / 48;       // 0..7, o = og*4 + r (wcT read broadcast)
        const float2* ptb = PT + (size_t)b * NJ * NF;
        float re0[4] = {0.f,0.f,0.f,0.f}, im0[4] = {0.f,0.f,0.f,0.f};
#pragma unroll 4
        for (int j = 0; j < NJ; ++j) {
            const float2 p  = ptb[(size_t)j * NF + f];
            const float4 w4 = *reinterpret_cast<const float4*>(&wcT[j][og * 4]);
            const float wv[4] = {w4.x, w4.y, w4.z, w4.w};
#pragma unroll
            for (int r = 0; r < 4; ++r) {
                re0[r] = fmaf(wv[r], p.x, re0[r]);
                im0[r] = fmaf(wv[r], p.y, im0[r]);
            }
        }
#pragma unroll
        for (int r = 0; r < 4; ++r)
            ampL[og * 4 + r][f] = sqrtf(re0[r] * re0[r] + im0[r] * im0[r]);
    }
    __syncthreads();

    // ---- phase 2: contraction + softplus + noise, reduce over o ----
    const int ol = tid & 31;           // o_local
    const int sg = tid >> 5;           // 0..11, s = sg*2 + k
    float aC[2] = {0.f, 0.f};
    float aN[2] = {0.f, 0.f};
    for (int f = 0; f < NF; ++f) {     // rolled: low pressure (round-6 lesson)
        const float a = ampL[ol][f];
#pragma unroll
        for (int k = 0; k < 2; ++k) {
            aC[k] = fmaf(a, wg[f * 20 + sg * 2 + k], aC[k]);
            aN[k] = fmaf(a, wn[f * 20 + sg * 2 + k], aN[k]);
        }
    }
    const int tr = training[0];
    const int o = ot * 32 + ol;
    float v[2];
#pragma unroll
    for (int k = 0; k < 2; ++k) {
        const int s = sg * 2 + k;
        float val = aC[k];
        if (tr && s < NS) {
            const float xx = aN[k];
            const float sp = fmaxf(xx, 0.f) + log1pf(expf(-fabsf(xx)));   // stable softplus
            val += noise[((size_t)b * NHID + o) * NS + s] * (sp + 0.01f);
        }
        v[k] = val;
    }
#pragma unroll
    for (int k = 0; k < 2; ++k) {
#pragma unroll
        for (int off = 1; off <= 16; off <<= 1)
            v[k] += __shfl_xor(v[k], off);     // reduce over ol (32-aligned lane groups)
    }
    if (ol == 0) {
        float* wp = wpart + ((size_t)(b * 16 + ot)) * 18;
#pragma unroll
        for (int k = 0; k < 2; ++k) {
            const int s = sg * 2 + k;
            if (s < NS) wp[s] = v[k];
        }
    }
}

// ---------------- K4: reduce 16 ot-partials per b, mean, top-k, softmax, scatter ----
__global__ __launch_bounds__(256) void k_final(const float* __restrict__ wpart,
                                               const int* __restrict__ top_k,
                                               float* __restrict__ out) {
    const int tid = threadIdx.x;
    const int b  = tid >> 4;
    const int ot = tid & 15;
    float acc[NS];
    const float* wp = wpart + ((size_t)(b * 16 + ot)) * 18;
#pragma unroll
    for (int s = 0; s < NS; ++s) acc[s] = wp[s];
#pragma unroll
    for (int s = 0; s < NS; ++s) {
#pragma unroll
        for (int off = 1; off <= 8; off <<= 1)
            acc[s] += __shfl_xor(acc[s], off);   // reduce over ot (16-aligned lane groups)
    }
    __shared__ float wf[NB][NS];
    if (ot == 0) {
#pragma unroll
        for (int s = 0; s < NS; ++s) wf[b][s] = acc[s] * (1.0f / 512.0f);
    }
    __syncthreads();
    if (tid < NB) {
        int k = top_k[0];
        if (k < 1) k = 1;
        if (k > NS) k = NS;
        float w[NS];
#pragma unroll
        for (int s = 0; s < NS; ++s) w[s] = wf[tid][s];
        float tv[NS];
        int   ti[NS];
        int used = 0;
        for (int kk = 0; kk < k; ++kk) {
            float best = -INFINITY;
            int bi = 0;
#pragma unroll
            for (int s = 0; s < NS; ++s) {
                if (!((used >> s) & 1) && w[s] > best) { best = w[s]; bi = s; } // '>' => lowest idx on tie
            }
            tv[kk] = best; ti[kk] = bi; used |= (1 << bi);
        }
        const float m = tv[0];
        float sum = 0.f;
        for (int kk = 0; kk < k; ++kk) { tv[kk] = expf(tv[kk] - m); sum += tv[kk]; }
        float outv[NS];
#pragma unroll
        for (int s = 0; s < NS; ++s) outv[s] = 0.f;
        for (int kk = 0; kk < k; ++kk) outv[ti[kk]] = tv[kk] / sum;
#pragma unroll
        for (int s = 0; s < NS; ++s) out[tid * NS + s] = outv[s];
    }
}

extern "C" void kernel_launch(void* const* d_in, const int* in_sizes, int n_in,
                              void* d_out, int out_size, void* d_ws, size_t ws_size,
                              hipStream_t stream) {
    const float* x        = (const float*)d_in[0];
    const float* in_w     = (const float*)d_in[1];
    // d_in[2] = in_b: irrelevant (contributes only to the dropped DC bin)
    const float* w_gate   = (const float*)d_in[3];
    const float* w_noise  = (const float*)d_in[4];
    const float* noise    = (const float*)d_in[5];
    const int*   training = (const int*)d_in[6];
    const int*   top_k    = (const int*)d_in[7];
    float* out = (float*)d_out;

    float* ws    = (float*)d_ws;
    float*  xm   = ws;                                    // 16*96*192 floats = 294912
    float2* PT   = (float2*)(xm + (size_t)NB * NT * NJ);  // 16*192*48 float2 = 147456
    float* wpart = (float*)(PT + (size_t)NB * NJ * NF);   // 16*16*18 = 4608 floats

    k_mean <<<NB * NT * NC, 256, 0, stream>>>(x, xm);
    k_dft  <<<NB * NF,      192, 0, stream>>>(xm, PT);
    k_ampw <<<NB * 16,      384, 0, stream>>>(in_w, PT, w_gate, w_noise, noise, training, wpart);
    k_final<<<1,            256, 0, stream>>>(wpart, top_k, out);
}